// Round 1
// baseline (81.220 us; speedup 1.0000x reference)
//
#include <hip/hip_runtime.h>
#include <hip/hip_bf16.h>

// ECE over logits (8,19,512,1024) f32, labels (8,512,1024) int.
// confidence = 1/sum(exp(l - lmax)); prediction = argmax (first-max, matches jnp).
// bin = clip(ceil(conf*15)-1, 0, 14)  ==  searchsorted(linspace(0,1,16), conf, left)-1 clipped.
// Stage 1: per-pixel -> LDS-replicated bin accumulators -> global atomics (ints exact, conf in double).
// Stage 2: tiny finalize kernel.

constexpr int NBINS = 15;
constexpr int NC    = 19;      // classes (fixed by reference)
constexpr int REP   = 8;       // LDS bin replicas to cut same-address atomic contention
constexpr int HWSH  = 19;      // H*W = 512*1024 = 2^19 (fixed by reference)

__global__ __launch_bounds__(256) void ece_partial_kernel(
    const float* __restrict__ logits,
    const int*   __restrict__ labels,
    double*       __restrict__ g_conf,   // [NBINS]
    unsigned int* __restrict__ g_cnt,    // [NBINS]
    unsigned int* __restrict__ g_corr,   // [NBINS]
    int P4)                              // number of 4-pixel groups
{
    __shared__ float    s_conf[NBINS][REP];
    __shared__ unsigned s_cnt [NBINS][REP];
    __shared__ unsigned s_corr[NBINS][REP];

    const int t = threadIdx.x;
    for (int i = t; i < NBINS * REP; i += blockDim.x) {
        (&s_conf[0][0])[i] = 0.0f;
        (&s_cnt [0][0])[i] = 0u;
        (&s_corr[0][0])[i] = 0u;
    }
    __syncthreads();

    const int rep    = t & (REP - 1);
    const int HW     = 1 << HWSH;
    const int stride = gridDim.x * blockDim.x;

    for (int g = blockIdx.x * blockDim.x + t; g < P4; g += stride) {
        const int p   = g << 2;              // first pixel of this 4-group
        const int n   = p >> HWSH;           // image index
        const int rem = p & (HW - 1);        // h*W + w within the image
        const float* base = logits + (((size_t)(n * NC)) << HWSH) + rem;

        // Load all 19 class values for 4 consecutive pixels (coalesced 16B/lane per plane).
        float v[NC][4];
        #pragma unroll
        for (int c = 0; c < NC; ++c) {
            const float4 x = *reinterpret_cast<const float4*>(base + ((size_t)c << HWSH));
            v[c][0] = x.x; v[c][1] = x.y; v[c][2] = x.z; v[c][3] = x.w;
        }
        const int4 lab = *reinterpret_cast<const int4*>(labels + p);
        const int labv[4] = { lab.x, lab.y, lab.z, lab.w };

        #pragma unroll
        for (int j = 0; j < 4; ++j) {
            float mx = v[0][j];
            int   am = 0;
            #pragma unroll
            for (int c = 1; c < NC; ++c) {
                if (v[c][j] > mx) { mx = v[c][j]; am = c; }  // strict > keeps first max (jnp.argmax)
            }
            float s = 0.0f;
            #pragma unroll
            for (int c = 0; c < NC; ++c) s += __expf(v[c][j] - mx);
            const float conf = 1.0f / s;

            int b = (int)ceilf(conf * 15.0f) - 1;
            b = b < 0 ? 0 : (b > NBINS - 1 ? NBINS - 1 : b);

            atomicAdd(&s_cnt [b][rep], 1u);
            atomicAdd(&s_conf[b][rep], conf);
            if (am == labv[j]) atomicAdd(&s_corr[b][rep], 1u);
        }
    }
    __syncthreads();

    if (t < NBINS) {
        unsigned cnt = 0u, cor = 0u;
        float cf = 0.0f;
        #pragma unroll
        for (int r = 0; r < REP; ++r) {
            cnt += s_cnt [t][r];
            cor += s_corr[t][r];
            cf  += s_conf[t][r];
        }
        if (cnt) {
            atomicAdd(&g_cnt [t], cnt);
            atomicAdd(&g_corr[t], cor);
            atomicAdd(&g_conf[t], (double)cf);
        }
    }
}

__global__ void ece_final_kernel(const double* __restrict__ g_conf,
                                 const unsigned int* __restrict__ g_cnt,
                                 const unsigned int* __restrict__ g_corr,
                                 float* __restrict__ out, float total)
{
    if (threadIdx.x == 0 && blockIdx.x == 0) {
        double e = 0.0;
        for (int b = 0; b < NBINS; ++b) {
            const double c = (double)g_cnt[b];
            if (c > 0.0) {
                const double acc = (double)g_corr[b] / c;
                const double avg = g_conf[b] / c;
                e += fabs(avg - acc) * (c / (double)total);
            }
        }
        out[0] = (float)e;
    }
}

extern "C" void kernel_launch(void* const* d_in, const int* in_sizes, int n_in,
                              void* d_out, int out_size, void* d_ws, size_t ws_size,
                              hipStream_t stream) {
    const float* logits = (const float*)d_in[0];
    const int*   labels = (const int*)d_in[1];   // harness converts integer inputs to int32
    float*       out    = (float*)d_out;

    const int P  = in_sizes[1];   // 8*512*1024 = 4,194,304 pixels
    const int P4 = P >> 2;

    // Workspace layout: [0..120) double conf_sum[15]; [128..188) uint cnt[15]; [192..252) uint corr[15]
    double*       g_conf = (double*)d_ws;
    unsigned int* g_cnt  = (unsigned int*)((char*)d_ws + 128);
    unsigned int* g_corr = (unsigned int*)((char*)d_ws + 192);

    hipMemsetAsync(d_ws, 0, 256, stream);  // deterministic re-zero every call

    int blocks = (P4 + 255) / 256;
    if (blocks > 2048) blocks = 2048;
    ece_partial_kernel<<<blocks, 256, 0, stream>>>(logits, labels, g_conf, g_cnt, g_corr, P4);
    ece_final_kernel<<<1, 64, 0, stream>>>(g_conf, g_cnt, g_corr, out, (float)P);
}